// Round 2
// baseline (605.711 us; speedup 1.0000x reference)
//
#include <hip/hip_runtime.h>

#define Bc 1024
#define Tc 512
#define Ic 64
#define Hc 32

// ---------------------------------------------------------------------------
// K1: xp[row][h] = sum_i x[row][i] * W_ih[h][i] + b_ih[h],  row = b*T + t.
// 256 threads / 128 rows per block. Coalesced float4 global loads staged
// TRANSPOSED into LDS (xT[i][r], pad +1 -> bank (i+r)%32, 2-way = free).
// Weights read wave-uniformly (readfirstlane on hbase) -> s_load / K-cache,
// zero vector-memory traffic for W. Each thread: 16 h x 64 i = 1024 FMAs.
// ---------------------------------------------------------------------------
__global__ __launch_bounds__(256) void xproj_kernel(
    const float* __restrict__ x, const float* __restrict__ Wih,
    const float* __restrict__ bih, float* __restrict__ xp)
{
    __shared__ float xT[Ic][128 + 1];   // 64 x 129 floats = 33 KB

    const int j = threadIdx.x;
    const size_t row0 = (size_t)blockIdx.x * 128;

    // Stage: 128 rows x 16 float4-chunks = 2048 chunks; 8 per thread,
    // consecutive threads -> consecutive 16B => fully coalesced.
#pragma unroll
    for (int m = 0; m < 8; ++m) {
        const int idx = m * 256 + j;
        const int r = idx >> 4;
        const int c = idx & 15;
        const float4 v = ((const float4*)(x + (row0 + r) * Ic))[c];
        xT[4 * c + 0][r] = v.x;
        xT[4 * c + 1][r] = v.y;
        xT[4 * c + 2][r] = v.z;
        xT[4 * c + 3][r] = v.w;
    }
    __syncthreads();

    // Wave-uniform h-half: waves 0,1 -> h 0..15; waves 2,3 -> h 16..31.
    const int hbase = __builtin_amdgcn_readfirstlane((j >> 7) * 16);
    const int r = j & 127;

    float acc[16];
#pragma unroll
    for (int hh = 0; hh < 16; ++hh) acc[hh] = bih[hbase + hh];

#pragma unroll 4
    for (int i = 0; i < Ic; ++i) {
        const float xv = xT[i][r];
#pragma unroll
        for (int hh = 0; hh < 16; ++hh)
            acc[hh] = fmaf(xv, Wih[(hbase + hh) * Ic + i], acc[hh]);
    }

    float4* dst = (float4*)(xp + (row0 + r) * Hc + hbase);
    dst[0] = make_float4(acc[0], acc[1], acc[2], acc[3]);
    dst[1] = make_float4(acc[4], acc[5], acc[6], acc[7]);
    dst[2] = make_float4(acc[8], acc[9], acc[10], acc[11]);
    dst[3] = make_float4(acc[12], acc[13], acc[14], acc[15]);
}

// ---------------------------------------------------------------------------
// K2: sequential scan. 1 wave / block, 2 batches / wave (lane = 32*half + h).
// h-broadcast via ds_swizzle or-mask (operates within 32-lane groups ->
// per-batch broadcast). NO LDS storage, NO __syncthreads -> no vmcnt(0)
// drain on the critical path; the xq prefetch (distance 2) floats freely.
// ---------------------------------------------------------------------------
#define BCAST_FMA(k, accv)                                                    \
    {                                                                         \
        const float v =                                                       \
            __int_as_float(__builtin_amdgcn_ds_swizzle(hb, (k) << 5));        \
        accv = fmaf(v, whh[(k)], accv);                                       \
    }
#define B4(k0)                                                                \
    BCAST_FMA((k0) + 0, a0)                                                   \
    BCAST_FMA((k0) + 1, a1)                                                   \
    BCAST_FMA((k0) + 2, a2)                                                   \
    BCAST_FMA((k0) + 3, a3)

__global__ __launch_bounds__(64) void rnn_kernel(
    const float* __restrict__ xp, const float* __restrict__ h0,
    const float* __restrict__ Whh, const float* __restrict__ bhh,
    const float* __restrict__ Wout, const float* __restrict__ bout,
    float* __restrict__ out)
{
    const int lane = threadIdx.x;
    const int h    = lane & 31;
    const int b    = blockIdx.x * 2 + (lane >> 5);

    float whh[Hc];
#pragma unroll
    for (int k = 0; k < Hc; ++k) whh[k] = Whh[h * Hc + k];
    const float bias = bhh[h];
    const float wo   = Wout[h];
    const float bo   = bout[0];

    float hval = h0[(size_t)b * Hc + h];

    const float* xprow = xp + (size_t)b * Tc * Hc + h;
    float* orow = out + (size_t)b * Tc;

    // software prefetch pipeline, distance 2
    float xq0 = xprow[0];
    float xq1 = xprow[Hc];

    for (int t = 0; t < Tc; ++t) {
        const int tp = (t + 2 < Tc) ? (t + 2) : (Tc - 1);
        const float xq2 = xprow[(size_t)tp * Hc];

        float a0 = xq0 + bias, a1 = 0.f, a2 = 0.f, a3 = 0.f;
        const int hb = __float_as_int(hval);
        B4(0) B4(4) B4(8) B4(12) B4(16) B4(20) B4(24) B4(28)
        const float a = (a0 + a1) + (a2 + a3);

        // tanh(a) = 1 - 2/(exp2(2*log2(e)*a) + 1); saturates correctly
        const float p = exp2f(a * 2.8853900817779268f);
        const float rr = __builtin_amdgcn_rcpf(p + 1.0f);
        hval = fmaf(-2.0f, rr, 1.0f);

        // out[b][t] = sum_h Wout[h]*h_new[h] + bout (butterfly within half)
        float po = wo * hval;
        po += __shfl_xor(po, 1);
        po += __shfl_xor(po, 2);
        po += __shfl_xor(po, 4);
        po += __shfl_xor(po, 8);
        po += __shfl_xor(po, 16);
        if (h == 0) orow[t] = po + bo;

        xq0 = xq1;
        xq1 = xq2;
    }

    // h_last: [1, B, H] appended after outs [B, T, 1]
    out[(size_t)Bc * Tc + (size_t)b * Hc + h] = hval;
}

extern "C" void kernel_launch(void* const* d_in, const int* in_sizes, int n_in,
                              void* d_out, int out_size, void* d_ws, size_t ws_size,
                              hipStream_t stream) {
    const float* x    = (const float*)d_in[0];
    const float* h0   = (const float*)d_in[1];
    const float* Wih  = (const float*)d_in[2];
    const float* bih  = (const float*)d_in[3];
    const float* Whh  = (const float*)d_in[4];
    const float* bhh  = (const float*)d_in[5];
    const float* Wout = (const float*)d_in[6];
    const float* bout = (const float*)d_in[7];
    float* out = (float*)d_out;
    float* xp  = (float*)d_ws;   // B*T*H fp32 = 64 MB scratch

    xproj_kernel<<<(Bc * Tc) / 128, 256, 0, stream>>>(x, Wih, bih, xp);
    rnn_kernel<<<Bc / 2, 64, 0, stream>>>(xp, h0, Whh, bhh, Wout, bout, out);
}

// Round 3
// 399.848 us; speedup vs baseline: 1.5149x; 1.5149x over previous
//
#include <hip/hip_runtime.h>

#define Bc 1024
#define Tc 512
#define Ic 64
#define Hc 32

// ---------------------------------------------------------------------------
// K1: xpt[b][h][t] = sum_i x[b][t][i]*W_ih[h][i] + b_ih[h]   (TRANSPOSED out)
// 2048 blocks x 128 threads; 256 rows/block, 2 rows/thread (weight loads
// amortized over 2 rows). x staged in 64 KB LDS, XOR-swizzled float4 chunks.
// Weights read at uniform addresses (float4) -> expect s_load_dwordx4.
// ---------------------------------------------------------------------------
__global__ __launch_bounds__(128) void xproj_kernel(
    const float* __restrict__ x, const float* __restrict__ Wih,
    const float* __restrict__ bih, float* __restrict__ xpt)
{
    __shared__ float4 xs4[256 * 16];   // 64 KB exactly

    const int j = threadIdx.x;
    const int row0 = blockIdx.x * 256;

    // Stage 256 rows x 16 chunks, coalesced reads, swizzled LDS writes.
    const float4* xg = (const float4*)(x + (size_t)row0 * Ic);
#pragma unroll
    for (int m = 0; m < 32; ++m) {
        const int idx = m * 128 + j;
        const int r = idx >> 4;
        const int c = idx & 15;
        xs4[r * 16 + (c ^ (r & 15))] = xg[idx];
    }
    __syncthreads();

    const float4* W4 = (const float4*)Wih;
    const int r1 = j, r2 = j + 128;

    float acc1[Hc], acc2[Hc];
#pragma unroll
    for (int h = 0; h < Hc; ++h) { const float bv = bih[h]; acc1[h] = bv; acc2[h] = bv; }

#pragma unroll 2
    for (int c = 0; c < 16; ++c) {
        const float4 xv1 = xs4[r1 * 16 + (c ^ (r1 & 15))];
        const float4 xv2 = xs4[r2 * 16 + (c ^ (r2 & 15))];
#pragma unroll
        for (int h = 0; h < Hc; ++h) {
            const float4 w = W4[h * 16 + c];   // uniform address -> s_load
            acc1[h] = fmaf(xv1.x, w.x, fmaf(xv1.y, w.y,
                      fmaf(xv1.z, w.z, fmaf(xv1.w, w.w, acc1[h]))));
            acc2[h] = fmaf(xv2.x, w.x, fmaf(xv2.y, w.y,
                      fmaf(xv2.z, w.z, fmaf(xv2.w, w.w, acc2[h]))));
        }
    }

    // Transposed stores: lane-consecutive t => coalesced dword stores.
    {
        const int g = row0 + r1;
        float* dst = xpt + (((size_t)(g >> 9) * Hc) << 9) + (g & 511);
#pragma unroll
        for (int h = 0; h < Hc; ++h) dst[h << 9] = acc1[h];
    }
    {
        const int g = row0 + r2;
        float* dst = xpt + (((size_t)(g >> 9) * Hc) << 9) + (g & 511);
#pragma unroll
        for (int h = 0; h < Hc; ++h) dst[h << 9] = acc2[h];
    }
}

// ---------------------------------------------------------------------------
// K2: sequential scan. 1024 blocks x 64 threads = 1 batch/wave (lanes 32-63
// mirror lanes 0-31; readlane is wave-wide so only one batch per wave).
// h-broadcast via v_readlane -> SGPR -> v_fmac (NO DS ops on critical path).
// xpt read 16 steps at a time (4x dwordx4, prefetched one block ahead).
// Output projection: per-step ds_write (off critical path) + one LDS reduce
// + one coalesced 16-wide store per 16 steps.
// ---------------------------------------------------------------------------
#define RL4(k0)                                                               \
    a0 = fmaf(__int_as_float(__builtin_amdgcn_readlane(hb, (k0) + 0)),        \
              whh[(k0) + 0], a0);                                             \
    a1 = fmaf(__int_as_float(__builtin_amdgcn_readlane(hb, (k0) + 1)),        \
              whh[(k0) + 1], a1);                                             \
    a2 = fmaf(__int_as_float(__builtin_amdgcn_readlane(hb, (k0) + 2)),        \
              whh[(k0) + 2], a2);                                             \
    a3 = fmaf(__int_as_float(__builtin_amdgcn_readlane(hb, (k0) + 3)),        \
              whh[(k0) + 3], a3);

__global__ __launch_bounds__(64) void rnn_kernel(
    const float* __restrict__ xpt, const float* __restrict__ h0,
    const float* __restrict__ Whh, const float* __restrict__ bhh,
    const float* __restrict__ Wout, const float* __restrict__ bout,
    float* __restrict__ out)
{
    const int lane = threadIdx.x;
    const int h    = lane & 31;
    const int b    = blockIdx.x;

    __shared__ float pbuf[2][16][34];   // [half][step][h], pad 34 for reduce

    float whh[Hc];
#pragma unroll
    for (int k = 0; k < Hc; ++k) whh[k] = Whh[h * Hc + k];
    const float bias = bhh[h];
    const float wo   = Wout[h];
    const float bo   = bout[0];

    float hval = h0[(size_t)b * Hc + h];   // lanes 32-63 mirror (harmless)

    const float* xrow = xpt + (((size_t)b * Hc) << 9) + ((size_t)h << 9);
    float* orow = out + (size_t)b * Tc;

    float4 xq[4], xqn[4];
#pragma unroll
    for (int q = 0; q < 4; ++q) xq[q] = ((const float4*)xrow)[q];

    for (int tb = 0; tb < Tc / 16; ++tb) {
        const int tbn = (tb + 1 < Tc / 16) ? tb + 1 : tb;
        const float4* nxt = (const float4*)(xrow + tbn * 16);
#pragma unroll
        for (int q = 0; q < 4; ++q) xqn[q] = nxt[q];   // prefetch, 16-step lead

#pragma unroll
        for (int u = 0; u < 16; ++u) {
            const float xv = ((const float*)xq)[u];    // const component
            float a0 = xv + bias, a1 = 0.f, a2 = 0.f, a3 = 0.f;
            const int hb = __float_as_int(hval);
            RL4(0) RL4(4) RL4(8) RL4(12) RL4(16) RL4(20) RL4(24) RL4(28)
            const float a = (a0 + a1) + (a2 + a3);
            // tanh(a) = 1 - 2/(exp2(2*log2(e)*a)+1); saturates at +-inf
            const float p  = __builtin_amdgcn_exp2f(a * 2.8853900817779268f);
            const float rr = __builtin_amdgcn_rcpf(p + 1.0f);
            hval = fmaf(-2.0f, rr, 1.0f);
            pbuf[lane >> 5][u][h] = wo * hval;         // fire-and-forget
        }

        __builtin_amdgcn_wave_barrier();

        // lanes 0-15: po[u] = sum_h pbuf[0][u][h]; coalesced 16-wide store
        if (lane < 16) {
            const float2* pr = (const float2*)pbuf[0][lane];  // 8B-aligned
            float2 sa = pr[0], sb = pr[1];
#pragma unroll
            for (int m = 2; m < 16; m += 2) {
                sa.x += pr[m].x;     sa.y += pr[m].y;
                sb.x += pr[m + 1].x; sb.y += pr[m + 1].y;
            }
            orow[tb * 16 + lane] = ((sa.x + sb.x) + (sa.y + sb.y)) + bo;
        }

#pragma unroll
        for (int q = 0; q < 4; ++q) xq[q] = xqn[q];
    }

    // h_last: [1, B, H] appended after outs [B, T, 1]
    if (lane < 32) out[(size_t)Bc * Tc + (size_t)b * Hc + h] = hval;
}

extern "C" void kernel_launch(void* const* d_in, const int* in_sizes, int n_in,
                              void* d_out, int out_size, void* d_ws, size_t ws_size,
                              hipStream_t stream) {
    const float* x    = (const float*)d_in[0];
    const float* h0   = (const float*)d_in[1];
    const float* Wih  = (const float*)d_in[2];
    const float* bih  = (const float*)d_in[3];
    const float* Whh  = (const float*)d_in[4];
    const float* bhh  = (const float*)d_in[5];
    const float* Wout = (const float*)d_in[6];
    const float* bout = (const float*)d_in[7];
    float* out = (float*)d_out;
    float* xpt = (float*)d_ws;   // xpt[b][h][t] fp32 = 64 MB scratch

    xproj_kernel<<<(Bc * Tc) / 256, 128, 0, stream>>>(x, Wih, bih, xpt);
    rnn_kernel<<<Bc, 64, 0, stream>>>(xpt, h0, Whh, bhh, Wout, bout, out);
}